// Round 13
// baseline (1198.385 us; speedup 1.0000x reference)
//
#include <hip/hip_runtime.h>
#include <math.h>

// Problem constants
constexpr int BG = 100;        // graphs
constexpr int NN = 1000;       // nodes per graph (level 1)
constexpr int EE = 1600000;    // edges
constexpr int NV = 100000;     // total level-1 nodes
constexpr int FD = 128;        // feature dim
constexpr int K1 = 800, K2 = 640, K3 = 512;

// ---- XLA/Eigen f32 tanh: clamped rational approximation ----
// PROVEN (r7): swapping ocml tanh for this dropped absmax 11.0 -> 2.5 (pass).
__device__ __forceinline__ float xla_tanh(float x) {
    const float kClamp = 7.90531110763549805f;
    const float a1 = 4.89352455891786e-03f, a3 = 6.37261928875436e-04f,
                a5 = 1.48572235717979e-05f, a7 = 5.12229709037114e-08f,
                a9 = -8.60467152213735e-11f, a11 = 2.00018790482477e-13f,
                a13 = -2.76076847742355e-16f;
    const float b0 = 4.89352518554385e-03f, b2 = 2.26843463243900e-03f,
                b4 = 1.18534705686654e-04f, b6 = 1.19825839466702e-06f;
    if (fabsf(x) < 4e-04f) return x;
    float xc = fminf(fmaxf(x, -kClamp), kClamp);
    float x2 = xc * xc;
    float p = fmaf(x2, a13, a11);
    p = fmaf(x2, p, a9);
    p = fmaf(x2, p, a7);
    p = fmaf(x2, p, a5);
    p = fmaf(x2, p, a3);
    p = fmaf(x2, p, a1);
    p = xc * p;
    float q = fmaf(x2, b6, b4);
    q = fmaf(x2, q, b2);
    q = fmaf(x2, q, b0);
    return p / q;
}

// ============ CSR build ============
__global__ __launch_bounds__(256) void zero_k(int* __restrict__ p, int n) {
    int i = blockIdx.x * 256 + threadIdx.x;
    if (i < n) p[i] = 0;
}
__global__ __launch_bounds__(256) void count_k(const int* __restrict__ dst,
                                               int* __restrict__ cnt) {
    int e = blockIdx.x * 256 + threadIdx.x;
    if (e < EE) atomicAdd(&cnt[dst[e]], 1);
}
__global__ __launch_bounds__(1024) void scan1_k(const int* __restrict__ cnt,
                                                int* __restrict__ excl,
                                                int* __restrict__ bsum, int n) {
    __shared__ int s[1024];
    int b = blockIdx.x, t = threadIdx.x, i = b * 1024 + t;
    int v = (i < n) ? cnt[i] : 0;
    s[t] = v; __syncthreads();
    for (int off = 1; off < 1024; off <<= 1) {
        int x = (t >= off) ? s[t - off] : 0;
        __syncthreads();
        s[t] += x;
        __syncthreads();
    }
    if (i < n) excl[i] = s[t] - v;
    if (t == 1023) bsum[b] = s[t];
}
__global__ void scan2_k(int* __restrict__ bsum, int nb) {
    if (threadIdx.x == 0) {
        int acc = 0;
        for (int b = 0; b < nb; ++b) { int v = bsum[b]; bsum[b] = acc; acc += v; }
    }
}
__global__ __launch_bounds__(256) void scan3_k(int* __restrict__ rowptr,
                                               const int* __restrict__ bsum,
                                               int* __restrict__ cursor, int n) {
    int i = blockIdx.x * 256 + threadIdx.x;
    if (i < n) {
        int v = rowptr[i] + bsum[i >> 10];
        rowptr[i] = v;
        cursor[i] = v;
    }
    if (i == 0) rowptr[n] = EE;
}
__global__ __launch_bounds__(256) void fill_k(const int* __restrict__ dst,
                                              int* __restrict__ cursor,
                                              int* __restrict__ eidx) {
    int e = blockIdx.x * 256 + threadIdx.x;
    if (e < EE) {
        int p = atomicAdd(&cursor[dst[e]], 1);
        eidx[p] = e;   // bucket order varies run-to-run; f64 accumulation is
                       // order-invariant at the f32 rounding level
    }
}
// cmap = map2 o map1 (level-3 composed relabeling)
__global__ __launch_bounds__(256) void compose_k(const int* __restrict__ m1,
                                                 const int* __restrict__ m2,
                                                 int* __restrict__ cm, int n) {
    int i = blockIdx.x * 256 + threadIdx.x;
    if (i < n) { int v = m1[i]; cm[i] = (v < 0) ? -1 : m2[v]; }
}

// ====== gather v3 (r11 WIN: out of top-5): 4 row-slots x 32 feat-threads ======
__global__ __launch_bounds__(128) void gather3_k(
    const float* __restrict__ feat, const int* __restrict__ src,
    const int* __restrict__ rowptr, const int* __restrict__ eidx,
    const int* __restrict__ map, float* __restrict__ agg)
{
    __shared__ int sS[128];
    __shared__ double sred[4][32][4];
    int d = blockIdx.x, t = threadIdx.x;
    int slot = t >> 5;        // 0..3
    int fg   = t & 31;        // feature group (4 floats each)
    int dm = d;
    if (map) { dm = map[d]; if (dm < 0) return; }   // uniform per block
    int beg = rowptr[d], end = rowptr[d + 1];
    double a0 = 0.0, a1 = 0.0, a2 = 0.0, a3 = 0.0;
    while (beg < end) {
        int chunk = min(128, end - beg);
        if (t < chunk) {
            int s = src[eidx[beg + t]];
            if (map) s = map[s];
            sS[t] = s;
        }
        __syncthreads();
        for (int i = slot; i < chunk; i += 4) {
            int s = sS[i];
            if (s >= 0) {
                float4 v = *(const float4*)(feat + (size_t)s * FD + fg * 4);
                a0 += (double)v.x; a1 += (double)v.y;
                a2 += (double)v.z; a3 += (double)v.w;
            }
        }
        __syncthreads();
        beg += chunk;
    }
    sred[slot][fg][0] = a0; sred[slot][fg][1] = a1;
    sred[slot][fg][2] = a2; sred[slot][fg][3] = a3;
    __syncthreads();
    if (slot == 0) {
        double r0 = sred[0][fg][0] + sred[1][fg][0] + sred[2][fg][0] + sred[3][fg][0];
        double r1 = sred[0][fg][1] + sred[1][fg][1] + sred[2][fg][1] + sred[3][fg][1];
        double r2 = sred[0][fg][2] + sred[1][fg][2] + sred[2][fg][2] + sred[3][fg][2];
        double r3 = sred[0][fg][3] + sred[1][fg][3] + sred[2][fg][3] + sred[3][fg][3];
        *(float4*)(agg + (size_t)dm * FD + fg * 4) =
            make_float4((float)r0, (float)r1, (float)r2, (float)r3);
    }
}

// --------- conv matmul v5: 8 rows x 4 cols per thread ---------
// r12 lesson: conv invariant at 188us across Occ 10%->34% => per-wave mix
// bound, not occupancy. Input-LDS bytes/FMA = 4/cols, weight bytes/FMA =
// 4/rows. r12 was rows=16,cols=2 (2 B/FMA LDS, LDS pipe at 75% of FMA pipe).
// Here rows=8,cols=4: LDS 1 B/FMA (16 b128 per 256 FMA), reads are
// half-wave broadcasts (same row across 32 lanes, conflict-free).
// Per-output k-chain statements textually identical (ascending k, same
// expression form, bias-at-end, relu) -> same contraction; residual ulp
// noise is in the class proven absorbed by score plateaus (r2 vs r5).
constexpr int TRR = 32;
constexpr int KS = 64;
constexpr int LDK2 = 68;
__global__ __launch_bounds__(128) void conv_mm5(
    const float* __restrict__ in, float* __restrict__ agg,
    const float* __restrict__ w_root, const float* __restrict__ w_rel,
    const float* __restrict__ bias)
{
    __shared__ float sA[TRR][LDK2];
    __shared__ float sI[TRR][LDK2];
    int r0 = blockIdx.x * TRR;
    int t = threadIdx.x;
    int rg = t >> 5;                    // row group 0..3 (8 rows each)
    int cg = t & 31;                    // col group (4 cols each)
    const float* wr = w_rel  + (size_t)(4 * cg) * FD;
    const float* wo = w_root + (size_t)(4 * cg) * FD;
    float acc[4][8];
    #pragma unroll
    for (int c = 0; c < 4; ++c)
        #pragma unroll
        for (int r = 0; r < 8; ++r) acc[c][r] = 0.f;

    #pragma unroll
    for (int ph = 0; ph < 2; ++ph) {
        int kb = ph * KS;
        if (ph) __syncthreads();        // phase-0 reads done before restage
        // stage 32 rows x 64 cols of both tiles: 1024 float4 slots
        #pragma unroll
        for (int q = 0; q < 8; ++q) {
            int idx = q * 128 + t;      // 0..1023
            int row = (idx >> 4) & 31;  // 0..31
            int c4  = idx & 15;         // 0..15 (float4 within 64-col slab)
            if (idx < 512) {
                float4 va = *(const float4*)(agg + (size_t)(r0 + row) * FD + kb + c4 * 4);
                *(float4*)&sA[row][c4 * 4] = va;
            } else {
                float4 vi = *(const float4*)(in + (size_t)(r0 + row) * FD + kb + c4 * 4);
                *(float4*)&sI[row][c4 * 4] = vi;
            }
        }
        __syncthreads();
        #pragma unroll 4
        for (int k0 = kb; k0 < kb + KS; k0 += 4) {
            float4 rv0 = *(const float4*)(wr + 0 * FD + k0);
            float4 rv1 = *(const float4*)(wr + 1 * FD + k0);
            float4 rv2 = *(const float4*)(wr + 2 * FD + k0);
            float4 rv3 = *(const float4*)(wr + 3 * FD + k0);
            float4 ov0 = *(const float4*)(wo + 0 * FD + k0);
            float4 ov1 = *(const float4*)(wo + 1 * FD + k0);
            float4 ov2 = *(const float4*)(wo + 2 * FD + k0);
            float4 ov3 = *(const float4*)(wo + 3 * FD + k0);
            int kl = k0 - kb;
            #pragma unroll
            for (int r = 0; r < 8; ++r) {
                float4 a = *(const float4*)&sA[rg * 8 + r][kl];
                float4 b = *(const float4*)&sI[rg * 8 + r][kl];
                acc[0][r] += a.x * rv0.x + b.x * ov0.x;
                acc[0][r] += a.y * rv0.y + b.y * ov0.y;
                acc[0][r] += a.z * rv0.z + b.z * ov0.z;
                acc[0][r] += a.w * rv0.w + b.w * ov0.w;
                acc[1][r] += a.x * rv1.x + b.x * ov1.x;
                acc[1][r] += a.y * rv1.y + b.y * ov1.y;
                acc[1][r] += a.z * rv1.z + b.z * ov1.z;
                acc[1][r] += a.w * rv1.w + b.w * ov1.w;
                acc[2][r] += a.x * rv2.x + b.x * ov2.x;
                acc[2][r] += a.y * rv2.y + b.y * ov2.y;
                acc[2][r] += a.z * rv2.z + b.z * ov2.z;
                acc[2][r] += a.w * rv2.w + b.w * ov2.w;
                acc[3][r] += a.x * rv3.x + b.x * ov3.x;
                acc[3][r] += a.y * rv3.y + b.y * ov3.y;
                acc[3][r] += a.z * rv3.z + b.z * ov3.z;
                acc[3][r] += a.w * rv3.w + b.w * ov3.w;
            }
        }
    }
    float4 bv = *(const float4*)(bias + 4 * cg);
    #pragma unroll
    for (int r = 0; r < 8; ++r) {
        float v0 = bv.x + acc[0][r];
        float v1 = bv.y + acc[1][r];
        float v2 = bv.z + acc[2][r];
        float v3 = bv.w + acc[3][r];
        v0 = v0 > 0.f ? v0 : 0.f;
        v1 = v1 > 0.f ? v1 : 0.f;
        v2 = v2 > 0.f ? v2 : 0.f;
        v3 = v3 > 0.f ? v3 : 0.f;
        *(float4*)(agg + (size_t)(r0 + rg * 8 + r) * FD + 4 * cg) =
            make_float4(v0, v1, v2, v3);
    }
}

// ---------------- pw norm -> ||pw|| (f32) ----------------
__global__ __launch_bounds__(128) void norm_k(const float* __restrict__ pw,
                                              float* __restrict__ nrm)
{
    int t = threadIdx.x;
    float v = pw[t]; v *= v;
    #pragma unroll
    for (int off = 32; off; off >>= 1) v += __shfl_down(v, off);
    __shared__ float s[2];
    if ((t & 63) == 0) s[t >> 6] = v;
    __syncthreads();
    if (t == 0) nrm[0] = sqrtf(s[0] + s[1]);
}

// ------- scores: xla_tanh( (h . pw) / ||pw|| ), f64 dot (deterministic) -------
__global__ __launch_bounds__(256) void scores_k(
    const float* __restrict__ h, const float* __restrict__ pw,
    const float* __restrict__ nrm, float* __restrict__ out, int rows)
{
    int gid = blockIdx.x * 256 + threadIdx.x;
    int node = gid >> 6, lane = gid & 63;
    if (node >= rows) return;
    float2 hv = *(const float2*)(h + (size_t)node * FD + lane * 2);
    float2 wv = *(const float2*)(pw + lane * 2);
    double d = (double)hv.x * (double)wv.x + (double)hv.y * (double)wv.y;
    #pragma unroll
    for (int off = 32; off; off >>= 1) d += __shfl_down(d, off);
    if (lane == 0) {
        float arg = (float)d / nrm[0];
        out[node] = xla_tanh(arg);
    }
}

// ---- per-graph top-k: STABLE bitonic sort (value desc, index asc) ----
__global__ __launch_bounds__(512) void topk_k(
    const float* __restrict__ h, const float* __restrict__ scores,
    float* __restrict__ outx, int* __restrict__ mapping, int n_per, int k)
{
    __shared__ unsigned long long sk[1024];
    __shared__ int sel[1024];
    int b = blockIdx.x, tid = threadIdx.x;
    for (int i = tid; i < 1024; i += 512) {
        float f = (i < n_per) ? scores[b * n_per + i] : -INFINITY;
        unsigned u = __float_as_uint(f);
        u = (u & 0x80000000u) ? ~u : (u | 0x80000000u);
        sk[i] = ((unsigned long long)u << 32) | (unsigned)(1023 - i);
        sel[i] = -1;
    }
    __syncthreads();
    for (int ksz = 2; ksz <= 1024; ksz <<= 1) {
        for (int j = ksz >> 1; j; j >>= 1) {
            int i = ((tid & ~(j - 1)) << 1) | (tid & (j - 1));
            int p = i | j;
            bool up = ((i & ksz) == 0);
            unsigned long long ki = sk[i], kp = sk[p];
            if ((ki < kp) == up) { sk[i] = kp; sk[p] = ki; }
            __syncthreads();
        }
    }
    for (int i = tid; i < k; i += 512)
        sel[1023 - (unsigned)(sk[i] & 0xFFFFFFFFu)] = i;
    __syncthreads();
    for (int i = tid; i < n_per; i += 512)
        mapping[b * n_per + i] = (sel[i] >= 0) ? b * k + sel[i] : -1;
    for (int t = tid; t < k * 32; t += 512) {
        int nj = t >> 5, f4 = t & 31;
        unsigned long long kk = sk[nj];
        int old = 1023 - (unsigned)(kk & 0xFFFFFFFFu);
        unsigned u = (unsigned)(kk >> 32);
        float val = (u & 0x80000000u) ? __uint_as_float(u & 0x7FFFFFFFu)
                                      : __uint_as_float(~u);
        float4 v = *(const float4*)(h + (size_t)(b * n_per + old) * FD + f4 * 4);
        v.x *= val; v.y *= val; v.z *= val; v.w *= val;
        *(float4*)(outx + (size_t)(b * k + nj) * FD + f4 * 4) = v;
    }
}

// ------- global max+mean pool v2 (r10 WIN) -------
__global__ __launch_bounds__(1024) void gpool2_k(const float* __restrict__ xp,
                                                 float* __restrict__ g, int k)
{
    __shared__ float smx[8][128];
    __shared__ float ssm[8][128];
    int b = blockIdx.x, t = threadIdx.x;
    int rg = t >> 7;          // row group 0..7
    int f  = t & 127;         // feature
    float mx = -INFINITY, sm = 0.f;
    for (int j = rg; j < k; j += 8) {
        float v = xp[(size_t)(b * k + j) * FD + f];
        mx = fmaxf(mx, v);
        sm += v;
    }
    smx[rg][f] = mx;
    ssm[rg][f] = sm;
    __syncthreads();
    if (rg == 0) {
        float m = smx[0][f], s = ssm[0][f];
        #pragma unroll
        for (int q = 1; q < 8; ++q) { m = fmaxf(m, smx[q][f]); s += ssm[q][f]; }
        g[b * 256 + f]       += m;
        g[b * 256 + 128 + f] += s * (1.0f / k);
    }
}

// ---------------- MLP head + log_softmax ----------------
__global__ __launch_bounds__(256) void mlp_k(
    const float* __restrict__ g,
    const float* __restrict__ l1w, const float* __restrict__ l1b,
    const float* __restrict__ l2w, const float* __restrict__ l2b,
    const float* __restrict__ l3w, const float* __restrict__ l3b,
    float* __restrict__ out)
{
    __shared__ float s0[256], s1[128], s2[64], s3[10];
    int b = blockIdx.x, t = threadIdx.x;
    s0[t] = g[b * 256 + t];
    __syncthreads();
    if (t < 128) {
        float a = l1b[t];
        for (int kk = 0; kk < 256; ++kk) a += s0[kk] * l1w[t * 256 + kk];
        s1[t] = a > 0.f ? a : 0.f;
    }
    __syncthreads();
    if (t < 64) {
        float a = l2b[t];
        for (int kk = 0; kk < 128; ++kk) a += s1[kk] * l2w[t * 128 + kk];
        s2[t] = a > 0.f ? a : 0.f;
    }
    __syncthreads();
    if (t < 10) {
        float a = l3b[t];
        for (int kk = 0; kk < 64; ++kk) a += s2[kk] * l3w[t * 64 + kk];
        s3[t] = a;
    }
    __syncthreads();
    if (t == 0) {
        float m = s3[0];
        for (int i = 1; i < 10; ++i) m = fmaxf(m, s3[i]);
        float se = 0.f;
        for (int i = 0; i < 10; ++i) se += expf(s3[i] - m);
        float lse = m + logf(se);
        for (int i = 0; i < 10; ++i) out[b * 10 + i] = s3[i] - lse;
    }
}

extern "C" void kernel_launch(void* const* d_in, const int* in_sizes, int n_in,
                              void* d_out, int out_size, void* d_ws, size_t ws_size,
                              hipStream_t stream)
{
    const float* x       = (const float*)d_in[0];
    const int*   ei      = (const int*)d_in[1];
    const int*   src     = ei;
    const int*   dst     = ei + EE;
    const float* w_root1 = (const float*)d_in[2];
    const float* w_rel1  = (const float*)d_in[3];
    const float* b1      = (const float*)d_in[4];
    const float* pw1     = (const float*)d_in[5];
    const float* w_root2 = (const float*)d_in[6];
    const float* w_rel2  = (const float*)d_in[7];
    const float* b2      = (const float*)d_in[8];
    const float* pw2     = (const float*)d_in[9];
    const float* w_root3 = (const float*)d_in[10];
    const float* w_rel3  = (const float*)d_in[11];
    const float* b3      = (const float*)d_in[12];
    const float* pw3     = (const float*)d_in[13];
    const float* l1w     = (const float*)d_in[14];
    const float* l1b     = (const float*)d_in[15];
    const float* l2w     = (const float*)d_in[16];
    const float* l2b     = (const float*)d_in[17];
    const float* l3w     = (const float*)d_in[18];
    const float* l3b     = (const float*)d_in[19];
    float* out = (float*)d_out;

    // workspace layout
    float* A      = (float*)d_ws;              // 100000*128 f
    float* Bf     = A + (size_t)NV * FD;       // 80000*128 f
    float* scores = Bf + (size_t)80000 * FD;   // 100000 f
    float* g      = scores + NV;               // 25600 f
    float* nrm    = g + BG * 256;              // 64 f (pad)
    int*   map1   = (int*)(nrm + 64);          // 100000 i
    int*   map2   = map1 + NV;                 // 80000 i
    int*   map3   = map2 + 80000;              // 64000 i
    int*   rowptr = map3 + 64000;              // 100001 i (+pad)
    int*   cursor = rowptr + NV + 2;           // 100000 i
    int*   bsum   = cursor + NV;               // 128 i
    int*   eidx   = bsum + 128;                // 1600000 i
    int*   cmap   = eidx + EE;                 // 100000 i

    const int NB_E = (EE + 255) / 256;         // 6250
    const int NB_V = (NV + 255) / 256;         // 391
    const int NB_S = (NV + 1023) / 1024;       // 98

    // ---------------- CSR build (once; reused for all 3 levels) ----------------
    zero_k<<<NB_V, 256, 0, stream>>>(cursor, NV);
    count_k<<<NB_E, 256, 0, stream>>>(dst, cursor);
    scan1_k<<<NB_S, 1024, 0, stream>>>(cursor, rowptr, bsum, NV);
    scan2_k<<<1, 64, 0, stream>>>(bsum, NB_S);
    scan3_k<<<NB_V, 256, 0, stream>>>(rowptr, bsum, cursor, NV);
    fill_k<<<NB_E, 256, 0, stream>>>(dst, cursor, eidx);

    hipMemsetAsync(g, 0, (size_t)BG * 256 * sizeof(float), stream);

    // ---------------- level 1 ----------------
    gather3_k<<<NV, 128, 0, stream>>>(x, src, rowptr, eidx, nullptr, A);
    conv_mm5<<<NV / TRR, 128, 0, stream>>>(x, A, w_root1, w_rel1, b1);
    norm_k<<<1, 128, 0, stream>>>(pw1, nrm);
    scores_k<<<NV / 4, 256, 0, stream>>>(A, pw1, nrm, scores, NV);
    topk_k<<<BG, 512, 0, stream>>>(A, scores, Bf, map1, NN, K1);
    gpool2_k<<<BG, 1024, 0, stream>>>(Bf, g, K1);

    // ---------------- level 2 ----------------
    gather3_k<<<NV, 128, 0, stream>>>(Bf, src, rowptr, eidx, map1, A);
    conv_mm5<<<(BG * K1) / TRR, 128, 0, stream>>>(Bf, A, w_root2, w_rel2, b2);
    norm_k<<<1, 128, 0, stream>>>(pw2, nrm);
    scores_k<<<(BG * K1) / 4, 256, 0, stream>>>(A, pw2, nrm, scores, BG * K1);
    topk_k<<<BG, 512, 0, stream>>>(A, scores, Bf, map2, K1, K2);
    gpool2_k<<<BG, 1024, 0, stream>>>(Bf, g, K2);

    // ---------------- level 3 ----------------
    compose_k<<<NB_V, 256, 0, stream>>>(map1, map2, cmap, NV);
    gather3_k<<<NV, 128, 0, stream>>>(Bf, src, rowptr, eidx, cmap, A);
    conv_mm5<<<(BG * K2) / TRR, 128, 0, stream>>>(Bf, A, w_root3, w_rel3, b3);
    norm_k<<<1, 128, 0, stream>>>(pw3, nrm);
    scores_k<<<(BG * K2) / 4, 256, 0, stream>>>(A, pw3, nrm, scores, BG * K2);
    topk_k<<<BG, 512, 0, stream>>>(A, scores, Bf, map3, K2, K3);
    gpool2_k<<<BG, 1024, 0, stream>>>(Bf, g, K3);

    // ---------------- head ----------------
    mlp_k<<<BG, 256, 0, stream>>>(g, l1w, l1b, l2w, l2b, l3w, l3b, out);
}

// Round 14
// 922.328 us; speedup vs baseline: 1.2993x; 1.2993x over previous
//
#include <hip/hip_runtime.h>
#include <math.h>

// Problem constants
constexpr int BG = 100;        // graphs
constexpr int NN = 1000;       // nodes per graph (level 1)
constexpr int EE = 1600000;    // edges
constexpr int NV = 100000;     // total level-1 nodes
constexpr int FD = 128;        // feature dim
constexpr int K1 = 800, K2 = 640, K3 = 512;

// ---- XLA/Eigen f32 tanh: clamped rational approximation ----
// PROVEN (r7): swapping ocml tanh for this dropped absmax 11.0 -> 2.5 (pass).
__device__ __forceinline__ float xla_tanh(float x) {
    const float kClamp = 7.90531110763549805f;
    const float a1 = 4.89352455891786e-03f, a3 = 6.37261928875436e-04f,
                a5 = 1.48572235717979e-05f, a7 = 5.12229709037114e-08f,
                a9 = -8.60467152213735e-11f, a11 = 2.00018790482477e-13f,
                a13 = -2.76076847742355e-16f;
    const float b0 = 4.89352518554385e-03f, b2 = 2.26843463243900e-03f,
                b4 = 1.18534705686654e-04f, b6 = 1.19825839466702e-06f;
    if (fabsf(x) < 4e-04f) return x;
    float xc = fminf(fmaxf(x, -kClamp), kClamp);
    float x2 = xc * xc;
    float p = fmaf(x2, a13, a11);
    p = fmaf(x2, p, a9);
    p = fmaf(x2, p, a7);
    p = fmaf(x2, p, a5);
    p = fmaf(x2, p, a3);
    p = fmaf(x2, p, a1);
    p = xc * p;
    float q = fmaf(x2, b6, b4);
    q = fmaf(x2, q, b2);
    q = fmaf(x2, q, b0);
    return p / q;
}

// ============ CSR build ============
__global__ __launch_bounds__(256) void zero_k(int* __restrict__ p, int n) {
    int i = blockIdx.x * 256 + threadIdx.x;
    if (i < n) p[i] = 0;
}
__global__ __launch_bounds__(256) void count_k(const int* __restrict__ dst,
                                               int* __restrict__ cnt) {
    int e = blockIdx.x * 256 + threadIdx.x;
    if (e < EE) atomicAdd(&cnt[dst[e]], 1);
}
__global__ __launch_bounds__(1024) void scan1_k(const int* __restrict__ cnt,
                                                int* __restrict__ excl,
                                                int* __restrict__ bsum, int n) {
    __shared__ int s[1024];
    int b = blockIdx.x, t = threadIdx.x, i = b * 1024 + t;
    int v = (i < n) ? cnt[i] : 0;
    s[t] = v; __syncthreads();
    for (int off = 1; off < 1024; off <<= 1) {
        int x = (t >= off) ? s[t - off] : 0;
        __syncthreads();
        s[t] += x;
        __syncthreads();
    }
    if (i < n) excl[i] = s[t] - v;
    if (t == 1023) bsum[b] = s[t];
}
__global__ void scan2_k(int* __restrict__ bsum, int nb) {
    if (threadIdx.x == 0) {
        int acc = 0;
        for (int b = 0; b < nb; ++b) { int v = bsum[b]; bsum[b] = acc; acc += v; }
    }
}
__global__ __launch_bounds__(256) void scan3_k(int* __restrict__ rowptr,
                                               const int* __restrict__ bsum,
                                               int* __restrict__ cursor, int n) {
    int i = blockIdx.x * 256 + threadIdx.x;
    if (i < n) {
        int v = rowptr[i] + bsum[i >> 10];
        rowptr[i] = v;
        cursor[i] = v;
    }
    if (i == 0) rowptr[n] = EE;
}
__global__ __launch_bounds__(256) void fill_k(const int* __restrict__ dst,
                                              int* __restrict__ cursor,
                                              int* __restrict__ eidx) {
    int e = blockIdx.x * 256 + threadIdx.x;
    if (e < EE) {
        int p = atomicAdd(&cursor[dst[e]], 1);
        eidx[p] = e;   // bucket order varies run-to-run; f64 accumulation is
                       // order-invariant at the f32 rounding level
    }
}
// cmap = map2 o map1 (level-3 composed relabeling)
__global__ __launch_bounds__(256) void compose_k(const int* __restrict__ m1,
                                                 const int* __restrict__ m2,
                                                 int* __restrict__ cm, int n) {
    int i = blockIdx.x * 256 + threadIdx.x;
    if (i < n) { int v = m1[i]; cm[i] = (v < 0) ? -1 : m2[v]; }
}

// ====== gather v4: gather3 + XCD-aware block swizzle (T1) ======
// gather is L2-reuse-heavy: each graph's 512KB feature slab is re-read ~16x
// by its 1000 node-blocks. Default dispatch round-robins consecutive blocks
// across the 8 XCDs -> every XCD touches all 100 graphs (51MB >> 4MB L2).
// Bijective swizzle d=(bid%8)*12500+bid/8 gives each XCD ~12.5 contiguous
// graphs (~6MB working set ~ L2). Same blocks, same per-node sums: bit-
// identical output, only scheduling locality changes.
__global__ __launch_bounds__(128) void gather3_k(
    const float* __restrict__ feat, const int* __restrict__ src,
    const int* __restrict__ rowptr, const int* __restrict__ eidx,
    const int* __restrict__ map, float* __restrict__ agg)
{
    __shared__ int sS[128];
    __shared__ double sred[4][32][4];
    int bid = blockIdx.x;
    int d = (bid & 7) * (NV / 8) + (bid >> 3);   // XCD swizzle (100000 % 8 == 0)
    int t = threadIdx.x;
    int slot = t >> 5;        // 0..3
    int fg   = t & 31;        // feature group (4 floats each)
    int dm = d;
    if (map) { dm = map[d]; if (dm < 0) return; }   // uniform per block
    int beg = rowptr[d], end = rowptr[d + 1];
    double a0 = 0.0, a1 = 0.0, a2 = 0.0, a3 = 0.0;
    while (beg < end) {
        int chunk = min(128, end - beg);
        if (t < chunk) {
            int s = src[eidx[beg + t]];
            if (map) s = map[s];
            sS[t] = s;
        }
        __syncthreads();
        for (int i = slot; i < chunk; i += 4) {
            int s = sS[i];
            if (s >= 0) {
                float4 v = *(const float4*)(feat + (size_t)s * FD + fg * 4);
                a0 += (double)v.x; a1 += (double)v.y;
                a2 += (double)v.z; a3 += (double)v.w;
            }
        }
        __syncthreads();
        beg += chunk;
    }
    sred[slot][fg][0] = a0; sred[slot][fg][1] = a1;
    sred[slot][fg][2] = a2; sred[slot][fg][3] = a3;
    __syncthreads();
    if (slot == 0) {
        double r0 = sred[0][fg][0] + sred[1][fg][0] + sred[2][fg][0] + sred[3][fg][0];
        double r1 = sred[0][fg][1] + sred[1][fg][1] + sred[2][fg][1] + sred[3][fg][1];
        double r2 = sred[0][fg][2] + sred[1][fg][2] + sred[2][fg][2] + sred[3][fg][2];
        double r3 = sred[0][fg][3] + sred[1][fg][3] + sred[2][fg][3] + sred[3][fg][3];
        *(float4*)(agg + (size_t)dm * FD + fg * 4) =
            make_float4((float)r0, (float)r1, (float)r2, (float)r3);
    }
}

// --------- conv matmul v4 (REVERTED r13: proven 188us, bit-identical chain) ---------
// Design space measured: (16r,2c)TR32+Ksplit=188 (Occ 10% AND 34% -- occupancy
// insensitive); TR16(16r,2c)=260 (weight-BW bound); (8r,4c)=290 (weight VMEM
// + VGPR 132). (16r,2c) is the local optimum; LDS pipe ~75% of FMA is the
// structural limit of this scheme.
constexpr int TRR = 32;
constexpr int KS = 64;
constexpr int LDK2 = 68;
__global__ __launch_bounds__(128) void conv_mm4(
    const float* __restrict__ in, float* __restrict__ agg,
    const float* __restrict__ w_root, const float* __restrict__ w_rel,
    const float* __restrict__ bias)
{
    __shared__ float sA[TRR][LDK2];
    __shared__ float sI[TRR][LDK2];
    int r0 = blockIdx.x * TRR;
    int t = threadIdx.x;
    int g  = t >> 6;                    // row half (wave-uniform): 16 rows each
    int cp = t & 63;                    // column pair
    const float* wr0 = w_rel  + (size_t)(2 * cp) * FD;
    const float* wr1 = wr0 + FD;
    const float* wo0 = w_root + (size_t)(2 * cp) * FD;
    const float* wo1 = wo0 + FD;
    float acc[2][16];
    #pragma unroll
    for (int c = 0; c < 2; ++c)
        #pragma unroll
        for (int r = 0; r < 16; ++r) acc[c][r] = 0.f;

    #pragma unroll
    for (int ph = 0; ph < 2; ++ph) {
        int kb = ph * KS;
        if (ph) __syncthreads();        // phase-0 reads done before restage
        #pragma unroll
        for (int q = 0; q < 8; ++q) {
            int idx = q * 128 + t;      // 0..1023
            int row = (idx >> 4) & 31;  // 0..31
            int c4  = idx & 15;         // 0..15 (float4 within 64-col slab)
            if (idx < 512) {
                float4 va = *(const float4*)(agg + (size_t)(r0 + row) * FD + kb + c4 * 4);
                *(float4*)&sA[row][c4 * 4] = va;
            } else {
                float4 vi = *(const float4*)(in + (size_t)(r0 + row) * FD + kb + c4 * 4);
                *(float4*)&sI[row][c4 * 4] = vi;
            }
        }
        __syncthreads();
        for (int k0 = kb; k0 < kb + KS; k0 += 4) {
            float4 r0v = *(const float4*)(wr0 + k0);
            float4 r1v = *(const float4*)(wr1 + k0);
            float4 o0v = *(const float4*)(wo0 + k0);
            float4 o1v = *(const float4*)(wo1 + k0);
            int kl = k0 - kb;
            #pragma unroll
            for (int r = 0; r < 16; ++r) {
                float4 a = *(const float4*)&sA[g * 16 + r][kl];
                float4 b = *(const float4*)&sI[g * 16 + r][kl];
                acc[0][r] += a.x * r0v.x + b.x * o0v.x;
                acc[0][r] += a.y * r0v.y + b.y * o0v.y;
                acc[0][r] += a.z * r0v.z + b.z * o0v.z;
                acc[0][r] += a.w * r0v.w + b.w * o0v.w;
                acc[1][r] += a.x * r1v.x + b.x * o1v.x;
                acc[1][r] += a.y * r1v.y + b.y * o1v.y;
                acc[1][r] += a.z * r1v.z + b.z * o1v.z;
                acc[1][r] += a.w * r1v.w + b.w * o1v.w;
            }
        }
    }
    float b0 = bias[2 * cp], b1 = bias[2 * cp + 1];
    #pragma unroll
    for (int r = 0; r < 16; ++r) {
        float v0 = b0 + acc[0][r];
        float v1 = b1 + acc[1][r];
        v0 = v0 > 0.f ? v0 : 0.f;
        v1 = v1 > 0.f ? v1 : 0.f;
        *(float2*)(agg + (size_t)(r0 + g * 16 + r) * FD + 2 * cp) =
            make_float2(v0, v1);
    }
}

// ---------------- pw norm -> ||pw|| (f32) ----------------
__global__ __launch_bounds__(128) void norm_k(const float* __restrict__ pw,
                                              float* __restrict__ nrm)
{
    int t = threadIdx.x;
    float v = pw[t]; v *= v;
    #pragma unroll
    for (int off = 32; off; off >>= 1) v += __shfl_down(v, off);
    __shared__ float s[2];
    if ((t & 63) == 0) s[t >> 6] = v;
    __syncthreads();
    if (t == 0) nrm[0] = sqrtf(s[0] + s[1]);
}

// ------- scores: xla_tanh( (h . pw) / ||pw|| ), f64 dot (deterministic) -------
__global__ __launch_bounds__(256) void scores_k(
    const float* __restrict__ h, const float* __restrict__ pw,
    const float* __restrict__ nrm, float* __restrict__ out, int rows)
{
    int gid = blockIdx.x * 256 + threadIdx.x;
    int node = gid >> 6, lane = gid & 63;
    if (node >= rows) return;
    float2 hv = *(const float2*)(h + (size_t)node * FD + lane * 2);
    float2 wv = *(const float2*)(pw + lane * 2);
    double d = (double)hv.x * (double)wv.x + (double)hv.y * (double)wv.y;
    #pragma unroll
    for (int off = 32; off; off >>= 1) d += __shfl_down(d, off);
    if (lane == 0) {
        float arg = (float)d / nrm[0];
        out[node] = xla_tanh(arg);
    }
}

// ---- per-graph top-k: STABLE bitonic sort (value desc, index asc) ----
__global__ __launch_bounds__(512) void topk_k(
    const float* __restrict__ h, const float* __restrict__ scores,
    float* __restrict__ outx, int* __restrict__ mapping, int n_per, int k)
{
    __shared__ unsigned long long sk[1024];
    __shared__ int sel[1024];
    int b = blockIdx.x, tid = threadIdx.x;
    for (int i = tid; i < 1024; i += 512) {
        float f = (i < n_per) ? scores[b * n_per + i] : -INFINITY;
        unsigned u = __float_as_uint(f);
        u = (u & 0x80000000u) ? ~u : (u | 0x80000000u);
        sk[i] = ((unsigned long long)u << 32) | (unsigned)(1023 - i);
        sel[i] = -1;
    }
    __syncthreads();
    for (int ksz = 2; ksz <= 1024; ksz <<= 1) {
        for (int j = ksz >> 1; j; j >>= 1) {
            int i = ((tid & ~(j - 1)) << 1) | (tid & (j - 1));
            int p = i | j;
            bool up = ((i & ksz) == 0);
            unsigned long long ki = sk[i], kp = sk[p];
            if ((ki < kp) == up) { sk[i] = kp; sk[p] = ki; }
            __syncthreads();
        }
    }
    for (int i = tid; i < k; i += 512)
        sel[1023 - (unsigned)(sk[i] & 0xFFFFFFFFu)] = i;
    __syncthreads();
    for (int i = tid; i < n_per; i += 512)
        mapping[b * n_per + i] = (sel[i] >= 0) ? b * k + sel[i] : -1;
    for (int t = tid; t < k * 32; t += 512) {
        int nj = t >> 5, f4 = t & 31;
        unsigned long long kk = sk[nj];
        int old = 1023 - (unsigned)(kk & 0xFFFFFFFFu);
        unsigned u = (unsigned)(kk >> 32);
        float val = (u & 0x80000000u) ? __uint_as_float(u & 0x7FFFFFFFu)
                                      : __uint_as_float(~u);
        float4 v = *(const float4*)(h + (size_t)(b * n_per + old) * FD + f4 * 4);
        v.x *= val; v.y *= val; v.z *= val; v.w *= val;
        *(float4*)(outx + (size_t)(b * k + nj) * FD + f4 * 4) = v;
    }
}

// ------- global max+mean pool v2 (r10 WIN) -------
__global__ __launch_bounds__(1024) void gpool2_k(const float* __restrict__ xp,
                                                 float* __restrict__ g, int k)
{
    __shared__ float smx[8][128];
    __shared__ float ssm[8][128];
    int b = blockIdx.x, t = threadIdx.x;
    int rg = t >> 7;          // row group 0..7
    int f  = t & 127;         // feature
    float mx = -INFINITY, sm = 0.f;
    for (int j = rg; j < k; j += 8) {
        float v = xp[(size_t)(b * k + j) * FD + f];
        mx = fmaxf(mx, v);
        sm += v;
    }
    smx[rg][f] = mx;
    ssm[rg][f] = sm;
    __syncthreads();
    if (rg == 0) {
        float m = smx[0][f], s = ssm[0][f];
        #pragma unroll
        for (int q = 1; q < 8; ++q) { m = fmaxf(m, smx[q][f]); s += ssm[q][f]; }
        g[b * 256 + f]       += m;
        g[b * 256 + 128 + f] += s * (1.0f / k);
    }
}

// ---------------- MLP head + log_softmax ----------------
__global__ __launch_bounds__(256) void mlp_k(
    const float* __restrict__ g,
    const float* __restrict__ l1w, const float* __restrict__ l1b,
    const float* __restrict__ l2w, const float* __restrict__ l2b,
    const float* __restrict__ l3w, const float* __restrict__ l3b,
    float* __restrict__ out)
{
    __shared__ float s0[256], s1[128], s2[64], s3[10];
    int b = blockIdx.x, t = threadIdx.x;
    s0[t] = g[b * 256 + t];
    __syncthreads();
    if (t < 128) {
        float a = l1b[t];
        for (int kk = 0; kk < 256; ++kk) a += s0[kk] * l1w[t * 256 + kk];
        s1[t] = a > 0.f ? a : 0.f;
    }
    __syncthreads();
    if (t < 64) {
        float a = l2b[t];
        for (int kk = 0; kk < 128; ++kk) a += s1[kk] * l2w[t * 128 + kk];
        s2[t] = a > 0.f ? a : 0.f;
    }
    __syncthreads();
    if (t < 10) {
        float a = l3b[t];
        for (int kk = 0; kk < 64; ++kk) a += s2[kk] * l3w[t * 64 + kk];
        s3[t] = a;
    }
    __syncthreads();
    if (t == 0) {
        float m = s3[0];
        for (int i = 1; i < 10; ++i) m = fmaxf(m, s3[i]);
        float se = 0.f;
        for (int i = 0; i < 10; ++i) se += expf(s3[i] - m);
        float lse = m + logf(se);
        for (int i = 0; i < 10; ++i) out[b * 10 + i] = s3[i] - lse;
    }
}

extern "C" void kernel_launch(void* const* d_in, const int* in_sizes, int n_in,
                              void* d_out, int out_size, void* d_ws, size_t ws_size,
                              hipStream_t stream)
{
    const float* x       = (const float*)d_in[0];
    const int*   ei      = (const int*)d_in[1];
    const int*   src     = ei;
    const int*   dst     = ei + EE;
    const float* w_root1 = (const float*)d_in[2];
    const float* w_rel1  = (const float*)d_in[3];
    const float* b1      = (const float*)d_in[4];
    const float* pw1     = (const float*)d_in[5];
    const float* w_root2 = (const float*)d_in[6];
    const float* w_rel2  = (const float*)d_in[7];
    const float* b2      = (const float*)d_in[8];
    const float* pw2     = (const float*)d_in[9];
    const float* w_root3 = (const float*)d_in[10];
    const float* w_rel3  = (const float*)d_in[11];
    const float* b3      = (const float*)d_in[12];
    const float* pw3     = (const float*)d_in[13];
    const float* l1w     = (const float*)d_in[14];
    const float* l1b     = (const float*)d_in[15];
    const float* l2w     = (const float*)d_in[16];
    const float* l2b     = (const float*)d_in[17];
    const float* l3w     = (const float*)d_in[18];
    const float* l3b     = (const float*)d_in[19];
    float* out = (float*)d_out;

    // workspace layout
    float* A      = (float*)d_ws;              // 100000*128 f
    float* Bf     = A + (size_t)NV * FD;       // 80000*128 f
    float* scores = Bf + (size_t)80000 * FD;   // 100000 f
    float* g      = scores + NV;               // 25600 f
    float* nrm    = g + BG * 256;              // 64 f (pad)
    int*   map1   = (int*)(nrm + 64);          // 100000 i
    int*   map2   = map1 + NV;                 // 80000 i
    int*   map3   = map2 + 80000;              // 64000 i
    int*   rowptr = map3 + 64000;              // 100001 i (+pad)
    int*   cursor = rowptr + NV + 2;           // 100000 i
    int*   bsum   = cursor + NV;               // 128 i
    int*   eidx   = bsum + 128;                // 1600000 i
    int*   cmap   = eidx + EE;                 // 100000 i

    const int NB_E = (EE + 255) / 256;         // 6250
    const int NB_V = (NV + 255) / 256;         // 391
    const int NB_S = (NV + 1023) / 1024;       // 98

    // ---------------- CSR build (once; reused for all 3 levels) ----------------
    zero_k<<<NB_V, 256, 0, stream>>>(cursor, NV);
    count_k<<<NB_E, 256, 0, stream>>>(dst, cursor);
    scan1_k<<<NB_S, 1024, 0, stream>>>(cursor, rowptr, bsum, NV);
    scan2_k<<<1, 64, 0, stream>>>(bsum, NB_S);
    scan3_k<<<NB_V, 256, 0, stream>>>(rowptr, bsum, cursor, NV);
    fill_k<<<NB_E, 256, 0, stream>>>(dst, cursor, eidx);

    hipMemsetAsync(g, 0, (size_t)BG * 256 * sizeof(float), stream);

    // ---------------- level 1 ----------------
    gather3_k<<<NV, 128, 0, stream>>>(x, src, rowptr, eidx, nullptr, A);
    conv_mm4<<<NV / TRR, 128, 0, stream>>>(x, A, w_root1, w_rel1, b1);
    norm_k<<<1, 128, 0, stream>>>(pw1, nrm);
    scores_k<<<NV / 4, 256, 0, stream>>>(A, pw1, nrm, scores, NV);
    topk_k<<<BG, 512, 0, stream>>>(A, scores, Bf, map1, NN, K1);
    gpool2_k<<<BG, 1024, 0, stream>>>(Bf, g, K1);

    // ---------------- level 2 ----------------
    gather3_k<<<NV, 128, 0, stream>>>(Bf, src, rowptr, eidx, map1, A);
    conv_mm4<<<(BG * K1) / TRR, 128, 0, stream>>>(Bf, A, w_root2, w_rel2, b2);
    norm_k<<<1, 128, 0, stream>>>(pw2, nrm);
    scores_k<<<(BG * K1) / 4, 256, 0, stream>>>(A, pw2, nrm, scores, BG * K1);
    topk_k<<<BG, 512, 0, stream>>>(A, scores, Bf, map2, K1, K2);
    gpool2_k<<<BG, 1024, 0, stream>>>(Bf, g, K2);

    // ---------------- level 3 ----------------
    compose_k<<<NB_V, 256, 0, stream>>>(map1, map2, cmap, NV);
    gather3_k<<<NV, 128, 0, stream>>>(Bf, src, rowptr, eidx, cmap, A);
    conv_mm4<<<(BG * K2) / TRR, 128, 0, stream>>>(Bf, A, w_root3, w_rel3, b3);
    norm_k<<<1, 128, 0, stream>>>(pw3, nrm);
    scores_k<<<(BG * K2) / 4, 256, 0, stream>>>(A, pw3, nrm, scores, BG * K2);
    topk_k<<<BG, 512, 0, stream>>>(A, scores, Bf, map3, K2, K3);
    gpool2_k<<<BG, 1024, 0, stream>>>(Bf, g, K3);

    // ---------------- head ----------------
    mlp_k<<<BG, 256, 0, stream>>>(g, l1w, l1b, l2w, l2b, l3w, l3b, out);
}